// Round 19
// baseline (201.050 us; speedup 1.0000x reference)
//
#include <hip/hip_runtime.h>
#include <hip/hip_bf16.h>

// Problem constants
#define BS 256
#define EMB 768
#define HW 196          // 14*14
#define NMASK 16
#define HID 4096
#define OUT 256
#define NPROJ 4
#define MROWS 4096      // BS*NMASK

typedef __attribute__((ext_vector_type(8))) short bf16x8;
typedef __attribute__((ext_vector_type(4))) float f32x4;
typedef __attribute__((ext_vector_type(8))) unsigned short u16x8;

__device__ inline float bf2f(unsigned short u) {
    unsigned int x = ((unsigned int)u) << 16;
    return __builtin_bit_cast(float, x);
}
__device__ inline short f2bfs(float f) {
    return __builtin_bit_cast(short, __float2bfloat16(f));
}

// async global->LDS, 16B per lane; lds base must be wave-uniform
#define GL16(gptr, lptr)                                                     \
    __builtin_amdgcn_global_load_lds(                                        \
        (const __attribute__((address_space(1))) void*)(gptr),               \
        (__attribute__((address_space(3))) void*)(lptr), 16, 0, 0)

// ---------------------------------------------------------------------------
// Kernel 0: maskprep — per-b bf16 A-fragments (7*64*8 shorts) + inv areas,
// computed ONCE into global.  grid 256.
// ---------------------------------------------------------------------------
__global__ __launch_bounds__(256) void maskprep(
    const float* __restrict__ masks, short* __restrict__ afrG,
    float* __restrict__ invG)
{
    const int b = blockIdx.x, tid = threadIdx.x;
    const float* mb = masks + (size_t)b * NMASK * HW;
    short* ag = afrG + (size_t)b * 3584;
    for (int s = tid; s < 7 * 64; s += 256) {
        int m = s & 15, kb = ((s >> 4) & 3) * 8 + (s >> 6) * 32;
        bf16x8 v;
        #pragma unroll
        for (int j = 0; j < 8; ++j) {
            int kk = kb + j;
            v[j] = (kk < HW) ? f2bfs(mb[m * HW + kk]) : (short)0;
        }
        *(bf16x8*)(ag + s * 8) = v;
    }
    if (tid >= 192) {
        int l = tid - 192, m = l >> 2, q = l & 3;
        float a = 0.f;
        for (int hw = q; hw < HW; hw += 4) a += mb[m * HW + hw];
        a += __shfl_xor(a, 1);
        a += __shfl_xor(a, 2);
        if (q == 0) invG[b * NMASK + m] = 1.0f / fmaxf(a, 1.0f);
    }
}

// ---------------------------------------------------------------------------
// Kernel 1: pool_main — masked mean pooling via MFMA, register x loads +
// prestaged mask fragments.  grid 3072 (b = bid/12, ec = bid%12).
// Standalone (NOT fused with transposes: co-compiled branches share regalloc
// and squeeze VGPR to 36/48, killing the upfront-load ILP — R12/R18).
// Also emits mpB per-b pre-rounding column sums (verified path, R11/R18).
// ---------------------------------------------------------------------------
__global__ __launch_bounds__(256) void pool_main(
    const float* __restrict__ x, const short* __restrict__ afrG,
    const float* __restrict__ invG, __hip_bfloat16* __restrict__ pooledG,
    float* __restrict__ mpB)
{
    __shared__ __align__(16) short afr[3584];   // 7 KB
    __shared__ float inv[NMASK];
    const int bid = blockIdx.x;
    const int b = bid / 12, ec = bid % 12;
    const int tid = threadIdx.x, lane = tid & 63, w = tid >> 6;
    const int lc = lane & 15, l4 = lane >> 4;

    // issue x loads FIRST: thread's quarter-row of row e = ec*64 + w*16 + lc
    const int e = ec * 64 + w * 16 + lc;
    const float* xrow = x + ((size_t)b * EMB + e) * HW;
    float4 u[6][2];
    #pragma unroll
    for (int kc = 0; kc < 6; ++kc) {
        u[kc][0] = *(const float4*)(xrow + kc * 32 + l4 * 8);
        u[kc][1] = *(const float4*)(xrow + kc * 32 + l4 * 8 + 4);
    }
    float4 ut = (l4 == 0) ? *(const float4*)(xrow + 192)
                          : float4{0.f, 0.f, 0.f, 0.f};

    // stage prestaged fragments: 448 16B-chunks, 2 wave-rounds
    {
        const char* src = (const char*)(afrG + (size_t)b * 3584);
        #pragma unroll
        for (int r = 0; r < 2; ++r) {
            int cb = r * 256 + w * 64;            // wave-uniform chunk base
            if (cb < 448)
                GL16(src + (size_t)cb * 16 + (size_t)lane * 16,
                     (char*)afr + cb * 16);
        }
    }
    if (tid < NMASK) inv[tid] = invG[b * NMASK + tid];
    __syncthreads();   // drains x loads + fragment GL16s; orders inv

    const bf16x8* afv = (const bf16x8*)afr;
    f32x4 acc = {};
    #pragma unroll
    for (int kc = 0; kc < 6; ++kc) {
        bf16x8 af = afv[kc * 64 + lane];
        bf16x8 bf;
        bf[0] = f2bfs(u[kc][0].x); bf[1] = f2bfs(u[kc][0].y);
        bf[2] = f2bfs(u[kc][0].z); bf[3] = f2bfs(u[kc][0].w);
        bf[4] = f2bfs(u[kc][1].x); bf[5] = f2bfs(u[kc][1].y);
        bf[6] = f2bfs(u[kc][1].z); bf[7] = f2bfs(u[kc][1].w);
        acc = __builtin_amdgcn_mfma_f32_16x16x32_bf16(af, bf, acc, 0, 0, 0);
    }
    {   // tail K-chunk: k=192..195 valid (l4==0 only), A fragments zero-padded
        bf16x8 af = afv[6 * 64 + lane];
        bf16x8 bf = {};
        if (l4 == 0) {
            bf[0] = f2bfs(ut.x); bf[1] = f2bfs(ut.y);
            bf[2] = f2bfs(ut.z); bf[3] = f2bfs(ut.w);
        }
        acc = __builtin_amdgcn_mfma_f32_16x16x32_bf16(af, bf, acc, 0, 0, 0);
    }

    // epilogue: scale by inv[m]; emit mpB partials (pre-rounding sums)
    float msum = 0.f;
    #pragma unroll
    for (int j = 0; j < 4; ++j) {
        int m = l4 * 4 + j;
        float v = acc[j] * inv[m];
        msum += v;
        pooledG[((size_t)m * 256 + b) * EMB + e] = __float2bfloat16(v);
    }
    msum += __shfl_xor(msum, 16);
    msum += __shfl_xor(msum, 32);              // sum over all 16 m
    if (l4 == 0) mpB[(size_t)b * EMB + e] = msum;
}

// ---------------------------------------------------------------------------
// Kernel 2: fused prep — W1 transpose+cvt (3072), W2 transpose+cvt (1024),
// pooledG bf16 transpose (768).  grid 4864.
// ---------------------------------------------------------------------------
__global__ __launch_bounds__(256) void prep(
    const float* __restrict__ W1, const float* __restrict__ W2,
    const __hip_bfloat16* __restrict__ pg,
    __hip_bfloat16* __restrict__ W1T, __hip_bfloat16* __restrict__ W2T,
    __hip_bfloat16* __restrict__ pgT)
{
    __shared__ __align__(16) char sm[64 * 65 * 4];
    const int bid = blockIdx.x, tid = threadIdx.x;
    if (bid < 4096) {
        const float* src; __hip_bfloat16* dst; int R, C, x, y, z;
        if (bid < 3072) { z = bid / 768; int r = bid % 768; x = r % 64; y = r / 64;
                          src = W1; dst = W1T; R = EMB; C = HID; }
        else            { int b2 = bid - 3072; z = b2 / 256; int r = b2 % 256;
                          x = r % 4; y = r / 4; src = W2; dst = W2T; R = HID; C = OUT; }
        float (*tile)[65] = (float(*)[65])sm;
        const float* s = src + (size_t)z * R * C;
        __hip_bfloat16* d = dst + (size_t)z * R * C;
        const int c0 = x * 64, r0 = y * 64;
        for (int i = tid; i < 4096; i += 256) {
            int r = i >> 6, c = i & 63;
            tile[r][c] = s[(size_t)(r0 + r) * C + c0 + c];
        }
        __syncthreads();
        for (int i = tid; i < 4096; i += 256) {
            int c = i >> 6, r = i & 63;
            d[(size_t)(c0 + c) * R + r0 + r] = __float2bfloat16(tile[r][c]);
        }
    } else {
        const int b3 = bid - 4096;            // (12 x, 64 y)
        const int x = b3 % 12, y = b3 / 12;
        __hip_bfloat16 (*tile)[65] = (__hip_bfloat16(*)[65])sm;
        const int c0 = x * 64, r0 = y * 64;
        for (int i = tid; i < 4096; i += 256) {
            int r = i >> 6, c = i & 63;
            tile[r][c] = pg[(size_t)(r0 + r) * EMB + c0 + c];
        }
        __syncthreads();
        for (int i = tid; i < 4096; i += 256) {
            int c = i >> 6, r = i & 63;
            pgT[(size_t)(c0 + c) * MROWS + r0 + r] = tile[r][c];
        }
    }
}

// ---------------------------------------------------------------------------
// Kernel 3: C GEMM (split-K, partial stores): Cpart[kz][i][j]
// grid (6, 6, 8)  K-chunk = 512.
// ---------------------------------------------------------------------------
__global__ __launch_bounds__(256) void cgemm(
    const __hip_bfloat16* __restrict__ PT, float* __restrict__ Cpart)
{
    __shared__ __align__(16) __hip_bfloat16 As[128 * 32];
    __shared__ __align__(16) __hip_bfloat16 Bs[128 * 32];
    const int tid = threadIdx.x, lane = tid & 63, wid = tid >> 6;
    const int n0 = blockIdx.x * 128, m0 = blockIdx.y * 128, kbase = blockIdx.z * 512;
    float* Cp = Cpart + (size_t)blockIdx.z * EMB * EMB;
    const int wr = wid >> 1, wc = wid & 1;
    const int l4 = lane >> 4, lc = lane & 15;

    f32x4 acc[4][4] = {};
    for (int k0 = kbase; k0 < kbase + 512; k0 += 32) {
        __syncthreads();
        #pragma unroll
        for (int r = 0; r < 2; ++r) {
            int t = r * 256 + tid;
            int row = t >> 2, ko = (t & 3) * 8;
            GL16(PT + (size_t)(m0 + row) * MROWS + k0 + ko, &As[(r * 256 + wid * 64) * 8]);
        }
        #pragma unroll
        for (int r = 0; r < 2; ++r) {
            int t = r * 256 + tid;
            int row = t >> 2, ko = (t & 3) * 8;
            GL16(PT + (size_t)(n0 + row) * MROWS + k0 + ko, &Bs[(r * 256 + wid * 64) * 8]);
        }
        __syncthreads();
        const bf16x8* Av = (const bf16x8*)As;
        const bf16x8* Bv = (const bf16x8*)Bs;
        bf16x8 a[4], b[4];
        #pragma unroll
        for (int m = 0; m < 4; ++m) a[m] = Av[(wr * 64 + m * 16 + lc) * 4 + l4];
        #pragma unroll
        for (int n = 0; n < 4; ++n) b[n] = Bv[(wc * 64 + n * 16 + lc) * 4 + l4];
        #pragma unroll
        for (int m = 0; m < 4; ++m)
            #pragma unroll
            for (int n = 0; n < 4; ++n)
                acc[m][n] = __builtin_amdgcn_mfma_f32_16x16x32_bf16(a[m], b[n], acc[m][n], 0, 0, 0);
    }
    #pragma unroll
    for (int m = 0; m < 4; ++m)
        #pragma unroll
        for (int n = 0; n < 4; ++n)
            #pragma unroll
            for (int j = 0; j < 4; ++j) {
                int row = m0 + wr * 64 + m * 16 + l4 * 4 + j;
                int col = n0 + wc * 64 + n * 16 + lc;
                Cp[(size_t)row * EMB + col] = acc[m][n][j];
            }
}

// ---------------------------------------------------------------------------
// Kernel 4: blocks 0..575 reduce 8 Cpart slices -> Cbf bf16 (1/N fold);
// blocks 576..578 reduce mpB (256 partials) -> mp.
// ---------------------------------------------------------------------------
__global__ __launch_bounds__(256) void cvt_c(
    const float* __restrict__ Cpart, const float* __restrict__ mpB,
    __hip_bfloat16* __restrict__ Cbf, float* __restrict__ mp)
{
    const int bid = blockIdx.x, tid = threadIdx.x;
    if (bid < 576) {
        int i = (bid * 256 + tid) * 4;   // < 768*768
        float sx = 0.f, sy = 0.f, sz = 0.f, sw = 0.f;
        #pragma unroll
        for (int kz = 0; kz < 8; ++kz) {
            float4 v = *(const float4*)(Cpart + (size_t)kz * EMB * EMB + i);
            sx += v.x; sy += v.y; sz += v.z; sw += v.w;
        }
        const float s = 1.0f / 4096.0f;
        Cbf[i + 0] = __float2bfloat16(sx * s);
        Cbf[i + 1] = __float2bfloat16(sy * s);
        Cbf[i + 2] = __float2bfloat16(sz * s);
        Cbf[i + 3] = __float2bfloat16(sw * s);
    } else {
        int e = (bid - 576) * 256 + tid;      // < 768
        float s = 0.f;
        for (int b = 0; b < 256; ++b) s += mpB[(size_t)b * EMB + e];
        mp[e] = s * (1.0f / 4096.0f);
    }
}

// ---------------------------------------------------------------------------
// Kernel 5: U GEMM + fused stats (partial stores indexed by (bx*2+wc)).
// grid (6, 32, 4) -> 12 partial slices.
// ---------------------------------------------------------------------------
__global__ __launch_bounds__(256) void ugemm(
    const __hip_bfloat16* __restrict__ W1T, const __hip_bfloat16* __restrict__ Cbf,
    const float* __restrict__ mp,
    float* __restrict__ Eh2p, float* __restrict__ Mup)
{
    __shared__ __align__(16) __hip_bfloat16 As[128 * 32];
    __shared__ __align__(16) __hip_bfloat16 Bs[128 * 32];
    const int tid = threadIdx.x, lane = tid & 63, wid = tid >> 6;
    const int n0 = blockIdx.x * 128, m0 = blockIdx.y * 128, p = blockIdx.z;
    const __hip_bfloat16* Ap = W1T + (size_t)p * HID * EMB;
    const int wr = wid >> 1, wc = wid & 1;
    const int l4 = lane >> 4, lc = lane & 15;

    f32x4 acc[4][4] = {};
    for (int k0 = 0; k0 < EMB; k0 += 32) {
        __syncthreads();
        #pragma unroll
        for (int r = 0; r < 2; ++r) {
            int t = r * 256 + tid;
            int row = t >> 2, ko = (t & 3) * 8;
            GL16(Ap + (size_t)(m0 + row) * EMB + k0 + ko, &As[(r * 256 + wid * 64) * 8]);
        }
        #pragma unroll
        for (int r = 0; r < 2; ++r) {
            int t = r * 256 + tid;
            int row = t >> 2, ko = (t & 3) * 8;
            GL16(Cbf + (size_t)(n0 + row) * EMB + k0 + ko, &Bs[(r * 256 + wid * 64) * 8]);
        }
        __syncthreads();
        const bf16x8* Av = (const bf16x8*)As;
        const bf16x8* Bv = (const bf16x8*)Bs;
        bf16x8 a[4], b[4];
        #pragma unroll
        for (int m = 0; m < 4; ++m) a[m] = Av[(wr * 64 + m * 16 + lc) * 4 + l4];
        #pragma unroll
        for (int n = 0; n < 4; ++n) b[n] = Bv[(wc * 64 + n * 16 + lc) * 4 + l4];
        #pragma unroll
        for (int m = 0; m < 4; ++m)
            #pragma unroll
            for (int n = 0; n < 4; ++n)
                acc[m][n] = __builtin_amdgcn_mfma_f32_16x16x32_bf16(a[m], b[n], acc[m][n], 0, 0, 0);
    }

    float mpv[4];
    #pragma unroll
    for (int n = 0; n < 4; ++n) mpv[n] = mp[n0 + wc * 64 + n * 16 + lc];
    #pragma unroll
    for (int m = 0; m < 4; ++m) {
        #pragma unroll
        for (int j = 0; j < 4; ++j) {
            int row = m0 + wr * 64 + m * 16 + l4 * 4 + j;
            const __hip_bfloat16* wrow = Ap + (size_t)row * EMB;
            float e2 = 0.f, mu = 0.f;
            #pragma unroll
            for (int n = 0; n < 4; ++n) {
                int col = n0 + wc * 64 + n * 16 + lc;
                float wv = bf2f(__builtin_bit_cast(unsigned short, wrow[col]));
                e2 += acc[m][n][j] * wv;
                mu += mpv[n] * wv;
            }
            e2 += __shfl_xor(e2, 1); e2 += __shfl_xor(e2, 2);
            e2 += __shfl_xor(e2, 4); e2 += __shfl_xor(e2, 8);
            mu += __shfl_xor(mu, 1); mu += __shfl_xor(mu, 2);
            mu += __shfl_xor(mu, 4); mu += __shfl_xor(mu, 8);
            if (lc == 0) {
                size_t idx = (((size_t)blockIdx.x * 2 + wc) * NPROJ + p) * HID + row;
                Eh2p[idx] = e2;
                Mup [idx] = mu;
            }
        }
    }
}

// ---------------------------------------------------------------------------
// Kernel 6: finalize (reduce 12 partials)
// ---------------------------------------------------------------------------
__global__ __launch_bounds__(256) void finalize(
    const float* __restrict__ Eh2p, const float* __restrict__ Mup,
    const float* __restrict__ gamma, const float* __restrict__ beta,
    float* __restrict__ sbuf, float* __restrict__ tbuf)
{
    int i = blockIdx.x * 256 + threadIdx.x;            // < 16384
    float e2 = 0.f, mu = 0.f;
    #pragma unroll
    for (int bx = 0; bx < 12; ++bx) {
        e2 += Eh2p[bx * (NPROJ * HID) + i];
        mu += Mup [bx * (NPROJ * HID) + i];
    }
    float var = e2 - mu * mu;
    float is  = rsqrtf(fmaxf(var, 0.0f) + 1e-5f);
    float sc  = gamma[i] * is;
    sbuf[i] = sc;
    tbuf[i] = beta[i] - mu * sc;
}

// ---------------------------------------------------------------------------
// Kernel 7: selected GEMM1 + fused BN+ReLU — 256x256 tile, 8 waves, BK=32,
// 3-slot LDS ring (96 KB), counted vmcnt(4).  grid (16, 16), 512 threads.
// ---------------------------------------------------------------------------
__global__ __launch_bounds__(512, 2) void gemm1_sel(
    const __hip_bfloat16* __restrict__ A, const __hip_bfloat16* __restrict__ W1T,
    const int* __restrict__ proj,
    const float* __restrict__ sbuf, const float* __restrict__ tbuf,
    __hip_bfloat16* __restrict__ hrelu)
{
    __shared__ __align__(16) short LS[3 * 16384];  // slot: A 8192 shorts | B 8192 shorts
    const int tid = threadIdx.x, lane = tid & 63, w = tid >> 6;
    const int wr = w >> 2, wc = w & 3;             // 2M x 4N waves
    const int lc = lane & 15, l4 = lane >> 4;
    const int n0 = blockIdx.x * 256, m0 = blockIdx.y * 256;
    const int p = proj[blockIdx.y];
    const __hip_bfloat16* Ag = A;
    const __hip_bfloat16* Bg = W1T + (size_t)p * HID * EMB;
    const bf16x8* LSv = (const bf16x8*)LS;

    auto STAGE = [&](int t) {
        const int sb = (t % 3) * 32768;            // byte base of slot
        #pragma unroll
        for (int ab = 0; ab < 2; ++ab) {
            const __hip_bfloat16* g = ab ? Bg : Ag;
            const int rbase = ab ? n0 : m0;
            #pragma unroll
            for (int i = 0; i < 2; ++i) {
                int c = (w * 2 + i) * 64 + lane;
                int row = c >> 2, ps = c & 3;
                int ls = ps ^ (row & 3);
                const __hip_bfloat16* src =
                    g + (size_t)(rbase + row) * EMB + t * 32 + ls * 8;
                GL16(src, (char*)LS + sb + ab * 16384 + (w * 2 + i) * 1024);
            }
        }
    };

    f32x4 acc[8][4] = {};

    STAGE(0);
    STAGE(1);
    asm volatile("s_waitcnt vmcnt(4)" ::: "memory");   // tile 0 resident
    __builtin_amdgcn_s_barrier();

    for (int t = 0; t < 24; ++t) {
        if (t + 2 < 24) STAGE(t + 2);
        const int vb = (t % 3) * 2048;

        bf16x8 bfr[4];
        #pragma unroll
        for (int nf = 0; nf < 4; ++nf) {
            int rb = wc * 64 + nf * 16 + lc;
            bfr[nf] = LSv[vb + 1024 + rb * 4 + (l4 ^ (rb & 3))];
        }
        #pragma unroll
        for (int q = 0; q < 4; ++q) {
            bf16x8 afr[2];
            #pragma unroll
            for (int m2 = 0; m2 < 2; ++m2) {
                int ra = wr * 128 + (q * 2 + m2) * 16 + lc;
                afr[m2] = LSv[vb + ra * 4 + (l4 ^ (ra & 3))];
            }
            __builtin_amdgcn_s_setprio(1);
            #pragma unroll
            for (int m2 = 0; m2 < 2; ++m2)
                #pragma unroll
                for (int nf = 0; nf < 4; ++nf)
                    acc[q * 2 + m2][nf] = __builtin_amdgcn_mfma_f32_16x16x32_bf16(
                        afr[m2], bfr[nf], acc[q * 2 + m2][nf], 0, 0, 0);
            __builtin_amdgcn_s_setprio(0);
        }

        if (t + 2 < 24) {
            asm volatile("s_waitcnt vmcnt(4)" ::: "memory");
            __builtin_amdgcn_s_barrier();
        } else if (t + 2 == 24) {
            asm volatile("s_waitcnt vmcnt(0)" ::: "memory");
            __builtin_amdgcn_s_barrier();
        }
    }

    // epilogue: BN + ReLU + store
    #pragma unroll
    for (int nf = 0; nf < 4; ++nf) {
        int col = n0 + wc * 64 + nf * 16 + lc;
        float s = sbuf[p * HID + col];
        float tt = tbuf[p * HID + col];
        #pragma unroll
        for (int mf = 0; mf < 8; ++mf)
            #pragma unroll
            for (int j = 0; j < 4; ++j) {
                int row = m0 + wr * 128 + mf * 16 + l4 * 4 + j;
                float v = fmaxf(acc[mf][nf][j] * s + tt, 0.0f);
                hrelu[(size_t)row * HID + col] = __float2bfloat16(v);
            }
    }
}

// ---------------------------------------------------------------------------
// Kernel 8: GEMM2 split-K, 128x128 tiles:
// grid (16 nmask, 2 bc, 8): z = ct*4+kz, K-chunk = 1024. Partial stores.
// ---------------------------------------------------------------------------
__global__ __launch_bounds__(256) void gemm2(
    const __hip_bfloat16* __restrict__ Hn, const __hip_bfloat16* __restrict__ W2T,
    const int* __restrict__ proj, float* __restrict__ Opart)
{
    __shared__ __align__(16) __hip_bfloat16 As[128 * 32];
    __shared__ __align__(16) __hip_bfloat16 Bs[128 * 32];
    const int tid = threadIdx.x, lane = tid & 63, wid = tid >> 6;
    const int nmask = blockIdx.x;
    const int bc    = blockIdx.y;
    const int ct    = blockIdx.z >> 2, kz = blockIdx.z & 3;
    const int p = proj[nmask];
    const __hip_bfloat16* Ap = Hn + (size_t)(nmask * 256 + bc * 128) * HID;
    const __hip_bfloat16* Bp = W2T + ((size_t)p * OUT + ct * 128) * HID;
    float* Op = Opart + (size_t)kz * MROWS * OUT;
    const int wr = wid >> 1, wc = wid & 1;
    const int l4 = lane >> 4, lc = lane & 15;

    f32x4 acc[4][4] = {};
    for (int k0 = kz * 1024; k0 < kz * 1024 + 1024; k0 += 32) {
        __syncthreads();
        #pragma unroll
        for (int r = 0; r < 2; ++r) {
            int t = r * 256 + tid;
            int row = t >> 2, ko = (t & 3) * 8;
            GL16(Ap + (size_t)row * HID + k0 + ko, &As[(r * 256 + wid * 64) * 8]);
        }
        #pragma unroll
        for (int r = 0; r < 2; ++r) {
            int t = r * 256 + tid;
            int row = t >> 2, ko = (t & 3) * 8;
            GL16(Bp + (size_t)row * HID + k0 + ko, &Bs[(r * 256 + wid * 64) * 8]);
        }
        __syncthreads();
        const bf16x8* Av = (const bf16x8*)As;
        const bf16x8* Bv = (const bf16x8*)Bs;
        bf16x8 a[4], b[4];
        #pragma unroll
        for (int m = 0; m < 4; ++m) a[m] = Av[(wr * 64 + m * 16 + lc) * 4 + l4];
        #pragma unroll
        for (int n = 0; n < 4; ++n) b[n] = Bv[(wc * 64 + n * 16 + lc) * 4 + l4];
        #pragma unroll
        for (int m = 0; m < 4; ++m)
            #pragma unroll
            for (int n = 0; n < 4; ++n)
                acc[m][n] = __builtin_amdgcn_mfma_f32_16x16x32_bf16(a[m], b[n], acc[m][n], 0, 0, 0);
    }

    #pragma unroll
    for (int m = 0; m < 4; ++m)
        #pragma unroll
        for (int n = 0; n < 4; ++n)
            #pragma unroll
            for (int j = 0; j < 4; ++j) {
                int bb = bc * 128 + wr * 64 + m * 16 + l4 * 4 + j;
                int oc = ct * 128 + wc * 64 + n * 16 + lc;
                Op[((size_t)bb * NMASK + nmask) * OUT + oc] = acc[m][n][j];
            }
}

// ---------------------------------------------------------------------------
// Kernel 9: reduce 4 Opart slices + b2 -> out ; fused mask_ids tail
// ---------------------------------------------------------------------------
__global__ __launch_bounds__(256) void reduce_out(
    const float* __restrict__ Opart, const float* __restrict__ b2,
    const int* __restrict__ proj, const int* __restrict__ mids,
    float* __restrict__ out)
{
    int i = (blockIdx.x * 256 + threadIdx.x) * 4;   // < 4096*256
    float sx = 0.f, sy = 0.f, sz = 0.f, sw = 0.f;
    #pragma unroll
    for (int kz = 0; kz < 4; ++kz) {
        float4 v = *(const float4*)(Opart + (size_t)kz * MROWS * OUT + i);
        sx += v.x; sy += v.y; sz += v.z; sw += v.w;
    }
    int nm = (i >> 8) & 15;
    int p  = proj[nm];
    float4 bv = *(const float4*)(b2 + p * OUT + (i & 255));
    float4 r;
    r.x = sx + bv.x; r.y = sy + bv.y; r.z = sz + bv.z; r.w = sw + bv.w;
    *(float4*)(out + i) = r;
    if (blockIdx.x < 16) {
        int t = blockIdx.x * 256 + threadIdx.x;     // < 4096
        out[(size_t)MROWS * OUT + t] = (float)mids[t];
    }
}

// ---------------------------------------------------------------------------
extern "C" void kernel_launch(void* const* d_in, const int* in_sizes, int n_in,
                              void* d_out, int out_size, void* d_ws, size_t ws_size,
                              hipStream_t stream)
{
    const float* x     = (const float*)d_in[0];
    const float* masks = (const float*)d_in[1];
    const int*   proj  = (const int*)d_in[2];
    const int*   mids  = (const int*)d_in[3];
    const float* W1    = (const float*)d_in[4];
    // d_in[5] = b1: cancels exactly under training-mode BN -> unused
    const float* gamma = (const float*)d_in[6];
    const float* beta  = (const float*)d_in[7];
    const float* W2    = (const float*)d_in[8];
    const float* b2    = (const float*)d_in[9];
    float* out = (float*)d_out;

    char* ws = (char*)d_ws;
    __hip_bfloat16* pooledG = (__hip_bfloat16*)(ws);                   //  6,291,456
    __hip_bfloat16* W1T     = (__hip_bfloat16*)(ws + 6291456);         // 25,165,824
    __hip_bfloat16* W2T     = (__hip_bfloat16*)(ws + 31457280);        //  8,388,608
    float*          mp      = (float*)(ws + 39845888);                 //      3,072
    float*          Eh2p    = (float*)(ws + 39848960);                 //    786,432
    float*          Mup     = (float*)(ws + 40635392);                 //    786,432
    float*          sbuf    = (float*)(ws + 41421824);                 //     65,536
    float*          tbuf    = (float*)(ws + 41487360);                 //     65,536
    short*          afrG    = (short*)(ws + 41552896);                 //  1,835,008
    float*          invG    = (float*)(ws + 43387904);                 //     16,384
    float*          mpB     = (float*)(ws + 43404288);                 //    786,432
    char* R = ws + 44190720;
    __hip_bfloat16* pooledT = (__hip_bfloat16*)(R);                    //  6,291,456
    float*          Cpart   = (float*)(R + 6291456);                   // 18,874,368
    __hip_bfloat16* Cbf     = (__hip_bfloat16*)(R + 25165824);         //  1,179,648
    __hip_bfloat16* hrelu   = (__hip_bfloat16*)(R);                    // 33,554,432 (after pooledT/Cpart/Cbf)
    float*          Opart   = (float*)(R + 33554432);                  // 16,777,216

    maskprep<<<BS, 256, 0, stream>>>(masks, afrG, invG);
    pool_main<<<3072, 256, 0, stream>>>(x, afrG, invG, pooledG, mpB);
    prep<<<4864, 256, 0, stream>>>(W1, W2, pooledG, W1T, W2T, pooledT);
    cgemm<<<dim3(6, 6, 8), 256, 0, stream>>>(pooledT, Cpart);
    cvt_c<<<579, 256, 0, stream>>>(Cpart, mpB, Cbf, mp);
    ugemm<<<dim3(6, 32, 4), 256, 0, stream>>>(W1T, Cbf, mp, Eh2p, Mup);
    finalize<<<(NPROJ * HID) / 256, 256, 0, stream>>>(Eh2p, Mup, gamma, beta, sbuf, tbuf);
    gemm1_sel<<<dim3(HID / 256, MROWS / 256), 512, 0, stream>>>(pooledG, W1T, proj, sbuf, tbuf, hrelu);
    gemm2<<<dim3(NMASK, 2, 8), 256, 0, stream>>>(hrelu, W2T, proj, Opart);
    reduce_out<<<(MROWS * OUT) / 1024, 256, 0, stream>>>(Opart, b2, proj, mids, out);
}

// Round 20
// 194.188 us; speedup vs baseline: 1.0353x; 1.0353x over previous
//
#include <hip/hip_runtime.h>
#include <hip/hip_bf16.h>

// Problem constants
#define BS 256
#define EMB 768
#define HW 196          // 14*14
#define NMASK 16
#define HID 4096
#define OUT 256
#define NPROJ 4
#define MROWS 4096      // BS*NMASK

typedef __attribute__((ext_vector_type(8))) short bf16x8;
typedef __attribute__((ext_vector_type(4))) float f32x4;
typedef __attribute__((ext_vector_type(8))) unsigned short u16x8;

__device__ inline float bf2f(unsigned short u) {
    unsigned int x = ((unsigned int)u) << 16;
    return __builtin_bit_cast(float, x);
}
__device__ inline short f2bfs(float f) {
    return __builtin_bit_cast(short, __float2bfloat16(f));
}

// async global->LDS, 16B per lane; lds base must be wave-uniform
#define GL16(gptr, lptr)                                                     \
    __builtin_amdgcn_global_load_lds(                                        \
        (const __attribute__((address_space(1))) void*)(gptr),               \
        (__attribute__((address_space(3))) void*)(lptr), 16, 0, 0)

// ---------------------------------------------------------------------------
// Kernel 0: maskprep — per-b bf16 A-fragments (7*64*8 shorts) + inv areas,
// computed ONCE into global (was redone per pool block).  grid 256.
// ---------------------------------------------------------------------------
__global__ __launch_bounds__(256) void maskprep(
    const float* __restrict__ masks, short* __restrict__ afrG,
    float* __restrict__ invG)
{
    const int b = blockIdx.x, tid = threadIdx.x;
    const float* mb = masks + (size_t)b * NMASK * HW;
    short* ag = afrG + (size_t)b * 3584;
    for (int s = tid; s < 7 * 64; s += 256) {
        int m = s & 15, kb = ((s >> 4) & 3) * 8 + (s >> 6) * 32;
        bf16x8 v;
        #pragma unroll
        for (int j = 0; j < 8; ++j) {
            int kk = kb + j;
            v[j] = (kk < HW) ? f2bfs(mb[m * HW + kk]) : (short)0;
        }
        *(bf16x8*)(ag + s * 8) = v;
    }
    if (tid >= 192) {
        int l = tid - 192, m = l >> 2, q = l & 3;
        float a = 0.f;
        for (int hw = q; hw < HW; hw += 4) a += mb[m * HW + hw];
        a += __shfl_xor(a, 1);
        a += __shfl_xor(a, 2);
        if (q == 0) invG[b * NMASK + m] = 1.0f / fmaxf(a, 1.0f);
    }
}

// ---------------------------------------------------------------------------
// Kernel 1: pool_main — masked mean pooling via MFMA, register x loads +
// prestaged mask fragments.  grid 3072 (b = bid/12, ec = bid%12; 64 e-rows
// per block, 4 waves x 16 rows).  13 upfront x loads/thread, 2 GL16 rounds
// for the 7KB fragment block, then 7 MFMAs.
// ---------------------------------------------------------------------------
__global__ __launch_bounds__(256) void pool_main(
    const float* __restrict__ x, const short* __restrict__ afrG,
    const float* __restrict__ invG, __hip_bfloat16* __restrict__ pooledG)
{
    __shared__ __align__(16) short afr[3584];   // 7 KB
    __shared__ float inv[NMASK];
    const int bid = blockIdx.x;
    const int b = bid / 12, ec = bid % 12;
    const int tid = threadIdx.x, lane = tid & 63, w = tid >> 6;
    const int lc = lane & 15, l4 = lane >> 4;

    // issue x loads FIRST: thread's quarter-row of row e = ec*64 + w*16 + lc
    const int e = ec * 64 + w * 16 + lc;
    const float* xrow = x + ((size_t)b * EMB + e) * HW;
    float4 u[6][2];
    #pragma unroll
    for (int kc = 0; kc < 6; ++kc) {
        u[kc][0] = *(const float4*)(xrow + kc * 32 + l4 * 8);
        u[kc][1] = *(const float4*)(xrow + kc * 32 + l4 * 8 + 4);
    }
    float4 ut = (l4 == 0) ? *(const float4*)(xrow + 192)
                          : float4{0.f, 0.f, 0.f, 0.f};

    // stage prestaged fragments: 448 16B-chunks, 2 wave-rounds
    {
        const char* src = (const char*)(afrG + (size_t)b * 3584);
        #pragma unroll
        for (int r = 0; r < 2; ++r) {
            int cb = r * 256 + w * 64;            // wave-uniform chunk base
            if (cb < 448)
                GL16(src + (size_t)cb * 16 + (size_t)lane * 16,
                     (char*)afr + cb * 16);
        }
    }
    if (tid < NMASK) inv[tid] = invG[b * NMASK + tid];
    __syncthreads();   // drains x loads + fragment GL16s; orders inv

    const bf16x8* afv = (const bf16x8*)afr;
    f32x4 acc = {};
    #pragma unroll
    for (int kc = 0; kc < 6; ++kc) {
        bf16x8 af = afv[kc * 64 + lane];
        bf16x8 bf;
        bf[0] = f2bfs(u[kc][0].x); bf[1] = f2bfs(u[kc][0].y);
        bf[2] = f2bfs(u[kc][0].z); bf[3] = f2bfs(u[kc][0].w);
        bf[4] = f2bfs(u[kc][1].x); bf[5] = f2bfs(u[kc][1].y);
        bf[6] = f2bfs(u[kc][1].z); bf[7] = f2bfs(u[kc][1].w);
        acc = __builtin_amdgcn_mfma_f32_16x16x32_bf16(af, bf, acc, 0, 0, 0);
    }
    {   // tail K-chunk: k=192..195 valid (l4==0 only), A fragments zero-padded
        bf16x8 af = afv[6 * 64 + lane];
        bf16x8 bf = {};
        if (l4 == 0) {
            bf[0] = f2bfs(ut.x); bf[1] = f2bfs(ut.y);
            bf[2] = f2bfs(ut.z); bf[3] = f2bfs(ut.w);
        }
        acc = __builtin_amdgcn_mfma_f32_16x16x32_bf16(af, bf, acc, 0, 0, 0);
    }

    // epilogue: D col(lc)=e, row(l4*4+j)=m ; scale by inv[m]
    #pragma unroll
    for (int j = 0; j < 4; ++j) {
        int m = l4 * 4 + j;
        pooledG[((size_t)m * 256 + b) * EMB + e] =
            __float2bfloat16(acc[j] * inv[m]);
    }
}

// ---------------------------------------------------------------------------
// Kernel 2: fused prep — W1 transpose+cvt (3072), W2 transpose+cvt (1024),
// pooledG bf16 transpose (768).  grid 4864.
// ---------------------------------------------------------------------------
__global__ __launch_bounds__(256) void prep(
    const float* __restrict__ W1, const float* __restrict__ W2,
    const __hip_bfloat16* __restrict__ pg,
    __hip_bfloat16* __restrict__ W1T, __hip_bfloat16* __restrict__ W2T,
    __hip_bfloat16* __restrict__ pgT)
{
    __shared__ __align__(16) char sm[64 * 65 * 4];
    const int bid = blockIdx.x, tid = threadIdx.x;
    if (bid < 4096) {
        const float* src; __hip_bfloat16* dst; int R, C, x, y, z;
        if (bid < 3072) { z = bid / 768; int r = bid % 768; x = r % 64; y = r / 64;
                          src = W1; dst = W1T; R = EMB; C = HID; }
        else            { int b2 = bid - 3072; z = b2 / 256; int r = b2 % 256;
                          x = r % 4; y = r / 4; src = W2; dst = W2T; R = HID; C = OUT; }
        float (*tile)[65] = (float(*)[65])sm;
        const float* s = src + (size_t)z * R * C;
        __hip_bfloat16* d = dst + (size_t)z * R * C;
        const int c0 = x * 64, r0 = y * 64;
        for (int i = tid; i < 4096; i += 256) {
            int r = i >> 6, c = i & 63;
            tile[r][c] = s[(size_t)(r0 + r) * C + c0 + c];
        }
        __syncthreads();
        for (int i = tid; i < 4096; i += 256) {
            int c = i >> 6, r = i & 63;
            d[(size_t)(c0 + c) * R + r0 + r] = __float2bfloat16(tile[r][c]);
        }
    } else {
        const int b3 = bid - 4096;            // (12 x, 64 y)
        const int x = b3 % 12, y = b3 / 12;
        __hip_bfloat16 (*tile)[65] = (__hip_bfloat16(*)[65])sm;
        const int c0 = x * 64, r0 = y * 64;
        for (int i = tid; i < 4096; i += 256) {
            int r = i >> 6, c = i & 63;
            tile[r][c] = pg[(size_t)(r0 + r) * EMB + c0 + c];
        }
        __syncthreads();
        for (int i = tid; i < 4096; i += 256) {
            int c = i >> 6, r = i & 63;
            pgT[(size_t)(c0 + c) * MROWS + r0 + r] = tile[r][c];
        }
    }
}

// ---------------------------------------------------------------------------
// Kernel 3: mp[e] = (1/4096) sum_r pooledT[e][r]
// ---------------------------------------------------------------------------
__global__ __launch_bounds__(256) void meanpool(
    const __hip_bfloat16* __restrict__ PT, float* __restrict__ mp)
{
    const int e = blockIdx.x, tid = threadIdx.x;
    const u16x8* p = (const u16x8*)(PT + (size_t)e * MROWS);
    u16x8 v1 = p[tid], v2 = p[tid + 256];
    float s = 0.f;
    #pragma unroll
    for (int j = 0; j < 8; ++j) s += bf2f((unsigned short)v1[j]) + bf2f((unsigned short)v2[j]);
    #pragma unroll
    for (int o = 1; o < 64; o <<= 1) s += __shfl_xor(s, o);
    __shared__ float wsum[4];
    if ((tid & 63) == 0) wsum[tid >> 6] = s;
    __syncthreads();
    if (tid == 0) mp[e] = (wsum[0] + wsum[1] + wsum[2] + wsum[3]) * (1.0f / 4096.0f);
}

// ---------------------------------------------------------------------------
// Kernel 4: C GEMM (split-K, partial stores): Cpart[kz][i][j]
// grid (6, 6, 8)  K-chunk = 512.
// ---------------------------------------------------------------------------
__global__ __launch_bounds__(256) void cgemm(
    const __hip_bfloat16* __restrict__ PT, float* __restrict__ Cpart)
{
    __shared__ __align__(16) __hip_bfloat16 As[128 * 32];
    __shared__ __align__(16) __hip_bfloat16 Bs[128 * 32];
    const int tid = threadIdx.x, lane = tid & 63, wid = tid >> 6;
    const int n0 = blockIdx.x * 128, m0 = blockIdx.y * 128, kbase = blockIdx.z * 512;
    float* Cp = Cpart + (size_t)blockIdx.z * EMB * EMB;
    const int wr = wid >> 1, wc = wid & 1;
    const int l4 = lane >> 4, lc = lane & 15;

    f32x4 acc[4][4] = {};
    for (int k0 = kbase; k0 < kbase + 512; k0 += 32) {
        __syncthreads();
        #pragma unroll
        for (int r = 0; r < 2; ++r) {
            int t = r * 256 + tid;
            int row = t >> 2, ko = (t & 3) * 8;
            GL16(PT + (size_t)(m0 + row) * MROWS + k0 + ko, &As[(r * 256 + wid * 64) * 8]);
        }
        #pragma unroll
        for (int r = 0; r < 2; ++r) {
            int t = r * 256 + tid;
            int row = t >> 2, ko = (t & 3) * 8;
            GL16(PT + (size_t)(n0 + row) * MROWS + k0 + ko, &Bs[(r * 256 + wid * 64) * 8]);
        }
        __syncthreads();
        const bf16x8* Av = (const bf16x8*)As;
        const bf16x8* Bv = (const bf16x8*)Bs;
        bf16x8 a[4], b[4];
        #pragma unroll
        for (int m = 0; m < 4; ++m) a[m] = Av[(wr * 64 + m * 16 + lc) * 4 + l4];
        #pragma unroll
        for (int n = 0; n < 4; ++n) b[n] = Bv[(wc * 64 + n * 16 + lc) * 4 + l4];
        #pragma unroll
        for (int m = 0; m < 4; ++m)
            #pragma unroll
            for (int n = 0; n < 4; ++n)
                acc[m][n] = __builtin_amdgcn_mfma_f32_16x16x32_bf16(a[m], b[n], acc[m][n], 0, 0, 0);
    }
    #pragma unroll
    for (int m = 0; m < 4; ++m)
        #pragma unroll
        for (int n = 0; n < 4; ++n)
            #pragma unroll
            for (int j = 0; j < 4; ++j) {
                int row = m0 + wr * 64 + m * 16 + l4 * 4 + j;
                int col = n0 + wc * 64 + n * 16 + lc;
                Cp[(size_t)row * EMB + col] = acc[m][n][j];
            }
}

// ---------------------------------------------------------------------------
// Kernel 5: reduce 8 Cpart slices -> Cbf bf16 with 1/N fold.  grid 576.
// ---------------------------------------------------------------------------
__global__ __launch_bounds__(256) void cvt_c(
    const float* __restrict__ Cpart, __hip_bfloat16* __restrict__ Cbf)
{
    int i = (blockIdx.x * 256 + threadIdx.x) * 4;   // < 768*768
    float sx = 0.f, sy = 0.f, sz = 0.f, sw = 0.f;
    #pragma unroll
    for (int kz = 0; kz < 8; ++kz) {
        float4 v = *(const float4*)(Cpart + (size_t)kz * EMB * EMB + i);
        sx += v.x; sy += v.y; sz += v.z; sw += v.w;
    }
    const float s = 1.0f / 4096.0f;
    Cbf[i + 0] = __float2bfloat16(sx * s);
    Cbf[i + 1] = __float2bfloat16(sy * s);
    Cbf[i + 2] = __float2bfloat16(sz * s);
    Cbf[i + 3] = __float2bfloat16(sw * s);
}

// ---------------------------------------------------------------------------
// Kernel 6: U GEMM + fused stats (partial stores indexed by (bx*2+wc)).
// grid (6, 32, 4) -> 12 partial slices.
// ---------------------------------------------------------------------------
__global__ __launch_bounds__(256) void ugemm(
    const __hip_bfloat16* __restrict__ W1T, const __hip_bfloat16* __restrict__ Cbf,
    const float* __restrict__ mp,
    float* __restrict__ Eh2p, float* __restrict__ Mup)
{
    __shared__ __align__(16) __hip_bfloat16 As[128 * 32];
    __shared__ __align__(16) __hip_bfloat16 Bs[128 * 32];
    const int tid = threadIdx.x, lane = tid & 63, wid = tid >> 6;
    const int n0 = blockIdx.x * 128, m0 = blockIdx.y * 128, p = blockIdx.z;
    const __hip_bfloat16* Ap = W1T + (size_t)p * HID * EMB;
    const int wr = wid >> 1, wc = wid & 1;
    const int l4 = lane >> 4, lc = lane & 15;

    f32x4 acc[4][4] = {};
    for (int k0 = 0; k0 < EMB; k0 += 32) {
        __syncthreads();
        #pragma unroll
        for (int r = 0; r < 2; ++r) {
            int t = r * 256 + tid;
            int row = t >> 2, ko = (t & 3) * 8;
            GL16(Ap + (size_t)(m0 + row) * EMB + k0 + ko, &As[(r * 256 + wid * 64) * 8]);
        }
        #pragma unroll
        for (int r = 0; r < 2; ++r) {
            int t = r * 256 + tid;
            int row = t >> 2, ko = (t & 3) * 8;
            GL16(Cbf + (size_t)(n0 + row) * EMB + k0 + ko, &Bs[(r * 256 + wid * 64) * 8]);
        }
        __syncthreads();
        const bf16x8* Av = (const bf16x8*)As;
        const bf16x8* Bv = (const bf16x8*)Bs;
        bf16x8 a[4], b[4];
        #pragma unroll
        for (int m = 0; m < 4; ++m) a[m] = Av[(wr * 64 + m * 16 + lc) * 4 + l4];
        #pragma unroll
        for (int n = 0; n < 4; ++n) b[n] = Bv[(wc * 64 + n * 16 + lc) * 4 + l4];
        #pragma unroll
        for (int m = 0; m < 4; ++m)
            #pragma unroll
            for (int n = 0; n < 4; ++n)
                acc[m][n] = __builtin_amdgcn_mfma_f32_16x16x32_bf16(a[m], b[n], acc[m][n], 0, 0, 0);
    }

    float mpv[4];
    #pragma unroll
    for (int n = 0; n < 4; ++n) mpv[n] = mp[n0 + wc * 64 + n * 16 + lc];
    #pragma unroll
    for (int m = 0; m < 4; ++m) {
        #pragma unroll
        for (int j = 0; j < 4; ++j) {
            int row = m0 + wr * 64 + m * 16 + l4 * 4 + j;
            const __hip_bfloat16* wrow = Ap + (size_t)row * EMB;
            float e2 = 0.f, mu = 0.f;
            #pragma unroll
            for (int n = 0; n < 4; ++n) {
                int col = n0 + wc * 64 + n * 16 + lc;
                float wv = bf2f(__builtin_bit_cast(unsigned short, wrow[col]));
                e2 += acc[m][n][j] * wv;
                mu += mpv[n] * wv;
            }
            e2 += __shfl_xor(e2, 1); e2 += __shfl_xor(e2, 2);
            e2 += __shfl_xor(e2, 4); e2 += __shfl_xor(e2, 8);
            mu += __shfl_xor(mu, 1); mu += __shfl_xor(mu, 2);
            mu += __shfl_xor(mu, 4); mu += __shfl_xor(mu, 8);
            if (lc == 0) {
                size_t idx = (((size_t)blockIdx.x * 2 + wc) * NPROJ + p) * HID + row;
                Eh2p[idx] = e2;
                Mup [idx] = mu;
            }
        }
    }
}

// ---------------------------------------------------------------------------
// Kernel 7: finalize (reduce 12 partials)
// ---------------------------------------------------------------------------
__global__ __launch_bounds__(256) void finalize(
    const float* __restrict__ Eh2p, const float* __restrict__ Mup,
    const float* __restrict__ gamma, const float* __restrict__ beta,
    float* __restrict__ sbuf, float* __restrict__ tbuf)
{
    int i = blockIdx.x * 256 + threadIdx.x;            // < 16384
    float e2 = 0.f, mu = 0.f;
    #pragma unroll
    for (int bx = 0; bx < 12; ++bx) {
        e2 += Eh2p[bx * (NPROJ * HID) + i];
        mu += Mup [bx * (NPROJ * HID) + i];
    }
    float var = e2 - mu * mu;
    float is  = rsqrtf(fmaxf(var, 0.0f) + 1e-5f);
    float sc  = gamma[i] * is;
    sbuf[i] = sc;
    tbuf[i] = beta[i] - mu * sc;
}

// ---------------------------------------------------------------------------
// Kernel 8: selected GEMM1 + fused BN+ReLU — 256x256 tile, 8 waves, BK=32,
// 3-slot LDS ring (96 KB), counted vmcnt(4).  grid (16, 16), 512 threads.
// ---------------------------------------------------------------------------
__global__ __launch_bounds__(512, 2) void gemm1_sel(
    const __hip_bfloat16* __restrict__ A, const __hip_bfloat16* __restrict__ W1T,
    const int* __restrict__ proj,
    const float* __restrict__ sbuf, const float* __restrict__ tbuf,
    __hip_bfloat16* __restrict__ hrelu)
{
    __shared__ __align__(16) short LS[3 * 16384];  // slot: A 8192 shorts | B 8192 shorts
    const int tid = threadIdx.x, lane = tid & 63, w = tid >> 6;
    const int wr = w >> 2, wc = w & 3;             // 2M x 4N waves
    const int lc = lane & 15, l4 = lane >> 4;
    const int n0 = blockIdx.x * 256, m0 = blockIdx.y * 256;
    const int p = proj[blockIdx.y];
    const __hip_bfloat16* Ag = A;
    const __hip_bfloat16* Bg = W1T + (size_t)p * HID * EMB;
    const bf16x8* LSv = (const bf16x8*)LS;

    auto STAGE = [&](int t) {
        const int sb = (t % 3) * 32768;            // byte base of slot
        #pragma unroll
        for (int ab = 0; ab < 2; ++ab) {
            const __hip_bfloat16* g = ab ? Bg : Ag;
            const int rbase = ab ? n0 : m0;
            #pragma unroll
            for (int i = 0; i < 2; ++i) {
                int c = (w * 2 + i) * 64 + lane;
                int row = c >> 2, ps = c & 3;
                int ls = ps ^ (row & 3);
                const __hip_bfloat16* src =
                    g + (size_t)(rbase + row) * EMB + t * 32 + ls * 8;
                GL16(src, (char*)LS + sb + ab * 16384 + (w * 2 + i) * 1024);
            }
        }
    };

    f32x4 acc[8][4] = {};

    STAGE(0);
    STAGE(1);
    asm volatile("s_waitcnt vmcnt(4)" ::: "memory");   // tile 0 resident
    __builtin_amdgcn_s_barrier();

    for (int t = 0; t < 24; ++t) {
        if (t + 2 < 24) STAGE(t + 2);
        const int vb = (t % 3) * 2048;

        bf16x8 bfr[4];
        #pragma unroll
        for (int nf = 0; nf < 4; ++nf) {
            int rb = wc * 64 + nf * 16 + lc;
            bfr[nf] = LSv[vb + 1024 + rb * 4 + (l4 ^ (rb & 3))];
        }
        #pragma unroll
        for (int q = 0; q < 4; ++q) {
            bf16x8 afr[2];
            #pragma unroll
            for (int m2 = 0; m2 < 2; ++m2) {
                int ra = wr * 128 + (q * 2 + m2) * 16 + lc;
                afr[m2] = LSv[vb + ra * 4 + (l4 ^ (ra & 3))];
            }
            __builtin_amdgcn_s_setprio(1);
            #pragma unroll
            for (int m2 = 0; m2 < 2; ++m2)
                #pragma unroll
                for (int nf = 0; nf < 4; ++nf)
                    acc[q * 2 + m2][nf] = __builtin_amdgcn_mfma_f32_16x16x32_bf16(
                        afr[m2], bfr[nf], acc[q * 2 + m2][nf], 0, 0, 0);
            __builtin_amdgcn_s_setprio(0);
        }

        if (t + 2 < 24) {
            asm volatile("s_waitcnt vmcnt(4)" ::: "memory");
            __builtin_amdgcn_s_barrier();
        } else if (t + 2 == 24) {
            asm volatile("s_waitcnt vmcnt(0)" ::: "memory");
            __builtin_amdgcn_s_barrier();
        }
    }

    // epilogue: BN + ReLU + store
    #pragma unroll
    for (int nf = 0; nf < 4; ++nf) {
        int col = n0 + wc * 64 + nf * 16 + lc;
        float s = sbuf[p * HID + col];
        float tt = tbuf[p * HID + col];
        #pragma unroll
        for (int mf = 0; mf < 8; ++mf)
            #pragma unroll
            for (int j = 0; j < 4; ++j) {
                int row = m0 + wr * 128 + mf * 16 + l4 * 4 + j;
                float v = fmaxf(acc[mf][nf][j] * s + tt, 0.0f);
                hrelu[(size_t)row * HID + col] = __float2bfloat16(v);
            }
    }
}

// ---------------------------------------------------------------------------
// Kernel 9: GEMM2 split-K, 128x128 tiles:
// grid (16 nmask, 2 bc, 8): z = ct*4+kz, K-chunk = 1024. Partial stores.
// ---------------------------------------------------------------------------
__global__ __launch_bounds__(256) void gemm2(
    const __hip_bfloat16* __restrict__ Hn, const __hip_bfloat16* __restrict__ W2T,
    const int* __restrict__ proj, float* __restrict__ Opart)
{
    __shared__ __align__(16) __hip_bfloat16 As[128 * 32];
    __shared__ __align__(16) __hip_bfloat16 Bs[128 * 32];
    const int tid = threadIdx.x, lane = tid & 63, wid = tid >> 6;
    const int nmask = blockIdx.x;
    const int bc    = blockIdx.y;
    const int ct    = blockIdx.z >> 2, kz = blockIdx.z & 3;
    const int p = proj[nmask];
    const __hip_bfloat16* Ap = Hn + (size_t)(nmask * 256 + bc * 128) * HID;
    const __hip_bfloat16* Bp = W2T + ((size_t)p * OUT + ct * 128) * HID;
    float* Op = Opart + (size_t)kz * MROWS * OUT;
    const int wr = wid >> 1, wc = wid & 1;
    const int l4 = lane >> 4, lc = lane & 15;

    f32x4 acc[4][4] = {};
    for (int k0 = kz * 1024; k0 < kz * 1024 + 1024; k0 += 32) {
        __syncthreads();
        #pragma unroll
        for (int r = 0; r < 2; ++r) {
            int t = r * 256 + tid;
            int row = t >> 2, ko = (t & 3) * 8;
            GL16(Ap + (size_t)row * HID + k0 + ko, &As[(r * 256 + wid * 64) * 8]);
        }
        #pragma unroll
        for (int r = 0; r < 2; ++r) {
            int t = r * 256 + tid;
            int row = t >> 2, ko = (t & 3) * 8;
            GL16(Bp + (size_t)row * HID + k0 + ko, &Bs[(r * 256 + wid * 64) * 8]);
        }
        __syncthreads();
        const bf16x8* Av = (const bf16x8*)As;
        const bf16x8* Bv = (const bf16x8*)Bs;
        bf16x8 a[4], b[4];
        #pragma unroll
        for (int m = 0; m < 4; ++m) a[m] = Av[(wr * 64 + m * 16 + lc) * 4 + l4];
        #pragma unroll
        for (int n = 0; n < 4; ++n) b[n] = Bv[(wc * 64 + n * 16 + lc) * 4 + l4];
        #pragma unroll
        for (int m = 0; m < 4; ++m)
            #pragma unroll
            for (int n = 0; n < 4; ++n)
                acc[m][n] = __builtin_amdgcn_mfma_f32_16x16x32_bf16(a[m], b[n], acc[m][n], 0, 0, 0);
    }

    #pragma unroll
    for (int m = 0; m < 4; ++m)
        #pragma unroll
        for (int n = 0; n < 4; ++n)
            #pragma unroll
            for (int j = 0; j < 4; ++j) {
                int bb = bc * 128 + wr * 64 + m * 16 + l4 * 4 + j;
                int oc = ct * 128 + wc * 64 + n * 16 + lc;
                Op[((size_t)bb * NMASK + nmask) * OUT + oc] = acc[m][n][j];
            }
}

// ---------------------------------------------------------------------------
// Kernel 10: reduce 4 Opart slices + b2 -> out ; fused mask_ids tail
// ---------------------------------------------------------------------------
__global__ __launch_bounds__(256) void reduce_out(
    const float* __restrict__ Opart, const float* __restrict__ b2,
    const int* __restrict__ proj, const int* __restrict__ mids,
    float* __restrict__ out)
{
    int i = (blockIdx.x * 256 + threadIdx.x) * 4;   // < 4096*256
    float sx = 0.f, sy = 0.f, sz = 0.f, sw = 0.f;
    #pragma unroll
    for (int kz = 0; kz < 4; ++kz) {
        float4 v = *(const float4*)(Opart + (size_t)kz * MROWS * OUT + i);
        sx += v.x; sy += v.y; sz += v.z; sw += v.w;
    }
    int nm = (i >> 8) & 15;
    int p  = proj[nm];
    float4 bv = *(const float4*)(b2 + p * OUT + (i & 255));
    float4 r;
    r.x = sx + bv.x; r.y = sy + bv.y; r.z = sz + bv.z; r.w = sw + bv.w;
    *(float4*)(out + i) = r;
    if (blockIdx.x < 16) {
        int t = blockIdx.x * 256 + threadIdx.x;     // < 4096
        out[(size_t)MROWS * OUT + t] = (float)mids[t];
    }
}

// ---------------------------------------------------------------------------
extern "C" void kernel_launch(void* const* d_in, const int* in_sizes, int n_in,
                              void* d_out, int out_size, void* d_ws, size_t ws_size,
                              hipStream_t stream)
{
    const float* x     = (const float*)d_in[0];
    const float* masks = (const float*)d_in[1];
    const int*   proj  = (const int*)d_in[2];
    const int*   mids  = (const int*)d_in[3];
    const float* W1    = (const float*)d_in[4];
    // d_in[5] = b1: cancels exactly under training-mode BN -> unused
    const float* gamma = (const float*)d_in[6];
    const float* beta  = (const float*)d_in[7];
    const float* W2    = (const float*)d_in[8];
    const float* b2    = (const float*)d_in[9];
    float* out = (float*)d_out;

    char* ws = (char*)d_ws;
    __hip_bfloat16* pooledG = (__hip_bfloat16*)(ws);                   //  6,291,456
    __hip_bfloat16* W1T     = (__hip_bfloat16*)(ws + 6291456);         // 25,165,824
    __hip_bfloat16* W2T     = (__hip_bfloat16*)(ws + 31457280);        //  8,388,608
    float*          mp      = (float*)(ws + 39845888);                 //      3,072
    float*          Eh2p    = (float*)(ws + 39848960);                 //    786,432
    float*          Mup     = (float*)(ws + 40635392);                 //    786,432
    float*          sbuf    = (float*)(ws + 41421824);                 //     65,536
    float*          tbuf    = (float*)(ws + 41487360);                 //     65,536
    short*          afrG    = (short*)(ws + 41552896);                 //  1,835,008
    float*          invG    = (float*)(ws + 43387904);                 //     16,384
    char* R = ws + 43404288;
    __hip_bfloat16* pooledT = (__hip_bfloat16*)(R);                    //  6,291,456
    float*          Cpart   = (float*)(R + 6291456);                   // 18,874,368
    __hip_bfloat16* Cbf     = (__hip_bfloat16*)(R + 25165824);         //  1,179,648
    __hip_bfloat16* hrelu   = (__hip_bfloat16*)(R);                    // 33,554,432 (after pooledT/Cpart/Cbf)
    float*          Opart   = (float*)(R + 33554432);                  // 16,777,216

    maskprep<<<BS, 256, 0, stream>>>(masks, afrG, invG);
    pool_main<<<3072, 256, 0, stream>>>(x, afrG, invG, pooledG);
    prep<<<4864, 256, 0, stream>>>(W1, W2, pooledG, W1T, W2T, pooledT);
    meanpool<<<EMB, 256, 0, stream>>>(pooledT, mp);
    cgemm<<<dim3(6, 6, 8), 256, 0, stream>>>(pooledT, Cpart);
    cvt_c<<<(EMB * EMB) / 1024, 256, 0, stream>>>(Cpart, Cbf);
    ugemm<<<dim3(6, 32, 4), 256, 0, stream>>>(W1T, Cbf, mp, Eh2p, Mup);
    finalize<<<(NPROJ * HID) / 256, 256, 0, stream>>>(Eh2p, Mup, gamma, beta, sbuf, tbuf);
    gemm1_sel<<<dim3(HID / 256, MROWS / 256), 512, 0, stream>>>(pooledG, W1T, proj, sbuf, tbuf, hrelu);
    gemm2<<<dim3(NMASK, 2, 8), 256, 0, stream>>>(hrelu, W2T, proj, Opart);
    reduce_out<<<(MROWS * OUT) / 1024, 256, 0, stream>>>(Opart, b2, proj, mids, out);
}